// Round 9
// baseline (1069.754 us; speedup 1.0000x reference)
//
#include <hip/hip_runtime.h>
#include <hip/hip_bf16.h>
#include <cstddef>

#define B_ 4
#define S_ 1024
#define E_ 1024
#define H_ 16
#define D_ 64
#define BH_ (B_*H_)

typedef __attribute__((ext_vector_type(8))) short short8;    // 8 bf16
typedef __attribute__((ext_vector_type(4))) float f32x4;
typedef __attribute__((ext_vector_type(4))) unsigned short us4;
typedef unsigned short u16;

__device__ inline u16 f2b(float x) {
    return __builtin_bit_cast(u16, __float2bfloat16(x));
}
__device__ inline float b2f(u16 u) {
    return __bfloat162float(__builtin_bit_cast(__hip_bfloat16, u));
}
__device__ inline void splitf(float x, u16& h, u16& l) {
    h = f2b(x); l = f2b(x - b2f(h));
}

// ---------------------------------------------------------------------------
// split fp32 array into hi/lo bf16 arrays (n4 = n/4)
// ---------------------------------------------------------------------------
__global__ __launch_bounds__(256) void split_pair(
    const float* __restrict__ in, u16* __restrict__ oh, u16* __restrict__ ol, int n4)
{
    int i = blockIdx.x * 256 + threadIdx.x;
    if (i >= n4) return;
    float4 v = ((const float4*)in)[i];
    us4 h, l;
    splitf(v.x, ((u16*)&h)[0], ((u16*)&l)[0]);
    splitf(v.y, ((u16*)&h)[1], ((u16*)&l)[1]);
    splitf(v.z, ((u16*)&h)[2], ((u16*)&l)[2]);
    splitf(v.w, ((u16*)&h)[3], ((u16*)&l)[3]);
    ((us4*)oh)[i] = h;
    ((us4*)ol)[i] = l;
}

// xsum[b][k] = sum_s x[b,s,k]
__global__ __launch_bounds__(256) void reduce_xsum(
    const float* __restrict__ x, float* __restrict__ xsum)
{
    int b = blockIdx.y;
    int k = blockIdx.x * 256 + threadIdx.x;
    float s = 0.f;
    const float* base = x + (size_t)b * S_ * E_ + k;
    for (int j = 0; j < S_; ++j) s += base[(size_t)j * E_];
    xsum[b * E_ + k] = s;
}

// t2n[b][n] = dot(W2[n], xsum[b]) + S*b2[n]
__global__ __launch_bounds__(256) void compute_t2k(
    const float* __restrict__ W2, const float* __restrict__ b2,
    const float* __restrict__ xsum, float* __restrict__ t2n)
{
    int b = blockIdx.y, n0 = blockIdx.x * 64;
    int w = threadIdx.x >> 6, lane = threadIdx.x & 63;
    const float* xs = xsum + b * E_;
    for (int nn = w; nn < 64; nn += 4) {
        int n = n0 + nn;
        const float* wr = W2 + (size_t)n * E_;
        float s = 0.f;
#pragma unroll
        for (int t = 0; t < 16; ++t) s = fmaf(wr[t * 64 + lane], xs[t * 64 + lane], s);
#pragma unroll
        for (int off = 1; off < 64; off <<= 1) s += __shfl_xor(s, off, 64);
        if (lane == 0) t2n[b * E_ + n] = s + 1024.0f * b2[n];
    }
}

// M[bh][a][c] = (1/8) * sum_d A[a][c][d] * t2[bh][d]
__global__ void compute_M(const float* __restrict__ A, const float* __restrict__ t2n,
                          float* __restrict__ Mout)
{
    int bh = blockIdx.x, b = bh >> 4, h = bh & 15;
    __shared__ float ts[64];
    if (threadIdx.x < 64) ts[threadIdx.x] = t2n[b * E_ + h * 64 + threadIdx.x];
    __syncthreads();
    int c = threadIdx.x & 63;
    int a0 = (threadIdx.x >> 6) * 16;
    for (int a = a0; a < a0 + 16; ++a) {
        float s = 0.f;
        const float* Ap = A + ((size_t)a * 64 + c) * 64;
#pragma unroll 8
        for (int d = 0; d < 64; ++d) s = fmaf(Ap[d], ts[d], s);
        Mout[((size_t)bh * 64 + a) * 64 + c] = s * 0.125f;
    }
}

// ---------------------------------------------------------------------------
// split-bf16 GEMM, 128x64 tile (round-7 verbatim — PASSING)
// ---------------------------------------------------------------------------
__global__ __launch_bounds__(256) void gemm_split128(
    const u16* __restrict__ Xh, const u16* __restrict__ Xl,
    const u16* __restrict__ Wh, const u16* __restrict__ Wl,
    const float* __restrict__ bias, float* __restrict__ outF,
    u16* __restrict__ oh, u16* __restrict__ ol, int mode)
{
    const int K = 1024;
    __shared__ __align__(16) u16 Xs_h[128 * 40];
    __shared__ __align__(16) u16 Xs_l[128 * 40];
    __shared__ __align__(16) u16 Ws_h[64 * 40];
    __shared__ __align__(16) u16 Ws_l[64 * 40];

    const int tid = threadIdx.x;
    const int w = tid >> 6, lane = tid & 63;
    const int waveM = w & 1, waveN = w >> 1;
    const int quad = lane >> 4, l16 = lane & 15;
    const int bm = blockIdx.x, bn = blockIdx.y;

    const int xrow = tid >> 1, xko = (tid & 1) * 16;
    const int wrow = tid >> 2, wko = (tid & 3) * 8;

    const u16* xh_g = Xh + (size_t)(bm * 128 + xrow) * K + xko;
    const u16* xl_g = Xl + (size_t)(bm * 128 + xrow) * K + xko;
    const u16* wh_g = Wh + (size_t)(bn * 64 + wrow) * K + wko;
    const u16* wl_g = Wl + (size_t)(bn * 64 + wrow) * K + wko;

    f32x4 acc[4][2] = {};

    for (int k0 = 0; k0 < K; k0 += 32) {
        uint4 xa = *(const uint4*)(xh_g + k0);
        uint4 xb = *(const uint4*)(xh_g + k0 + 8);
        uint4 xc = *(const uint4*)(xl_g + k0);
        uint4 xd = *(const uint4*)(xl_g + k0 + 8);
        uint4 wa = *(const uint4*)(wh_g + k0);
        uint4 wc = *(const uint4*)(wl_g + k0);
        __syncthreads();
        *(uint4*)&Xs_h[xrow * 40 + xko]     = xa;
        *(uint4*)&Xs_h[xrow * 40 + xko + 8] = xb;
        *(uint4*)&Xs_l[xrow * 40 + xko]     = xc;
        *(uint4*)&Xs_l[xrow * 40 + xko + 8] = xd;
        *(uint4*)&Ws_h[wrow * 40 + wko] = wa;
        *(uint4*)&Ws_l[wrow * 40 + wko] = wc;
        __syncthreads();

        short8 ah[4], al[4], bh_[2], bl_[2];
#pragma unroll
        for (int mt = 0; mt < 4; ++mt) {
            int r = (waveM * 64 + mt * 16 + l16) * 40 + quad * 8;
            ah[mt] = *(short8*)&Xs_h[r];
            al[mt] = *(short8*)&Xs_l[r];
        }
#pragma unroll
        for (int nt = 0; nt < 2; ++nt) {
            int r = (waveN * 32 + nt * 16 + l16) * 40 + quad * 8;
            bh_[nt] = *(short8*)&Ws_h[r];
            bl_[nt] = *(short8*)&Ws_l[r];
        }
#pragma unroll
        for (int mt = 0; mt < 4; ++mt)
#pragma unroll
            for (int nt = 0; nt < 2; ++nt) {
                acc[mt][nt] = __builtin_amdgcn_mfma_f32_16x16x32_bf16(ah[mt], bh_[nt], acc[mt][nt], 0, 0, 0);
                acc[mt][nt] = __builtin_amdgcn_mfma_f32_16x16x32_bf16(ah[mt], bl_[nt], acc[mt][nt], 0, 0, 0);
                acc[mt][nt] = __builtin_amdgcn_mfma_f32_16x16x32_bf16(al[mt], bh_[nt], acc[mt][nt], 0, 0, 0);
            }
    }

#pragma unroll
    for (int mt = 0; mt < 4; ++mt)
#pragma unroll
        for (int nt = 0; nt < 2; ++nt)
#pragma unroll
            for (int r = 0; r < 4; ++r) {
                int m = bm * 128 + waveM * 64 + mt * 16 + quad * 4 + r;
                int n = bn * 64 + waveN * 32 + nt * 16 + l16;
                float val = acc[mt][nt][r] + bias[n];
                int b = m >> 10, s = m & 1023, h = n >> 6, c = n & 63;
                size_t addr = ((size_t)(b * H_ + h) * S_ + s) * 64 + c;
                if (mode == 0) {
                    outF[addr] = val;
                } else {
                    u16 hh, ll; splitf(val, hh, ll);
                    oh[addr] = hh; ol[addr] = ll;
                }
            }
}

// q[bh][i][c] = sum_a p0[bh][i][a] * M[bh][a][c]; write hi/lo bf16
__global__ __launch_bounds__(256) void compute_q(
    const float* __restrict__ p0, const float* __restrict__ Min,
    u16* __restrict__ qh, u16* __restrict__ ql)
{
    int bh = blockIdx.y, i0 = blockIdx.x * 16;
    __shared__ float Ms[64 * 68];
    __shared__ float p0s[16 * 64];
    const float* base = p0 + ((size_t)bh * S_ + i0) * 64;
    for (int t = threadIdx.x; t < 4096; t += 256)
        Ms[(t >> 6) * 68 + (t & 63)] = Min[(size_t)bh * 4096 + t];
    for (int t = threadIdx.x; t < 1024; t += 256) p0s[t] = base[t];
    __syncthreads();
    int c = threadIdx.x & 63, il = threadIdx.x >> 6;
#pragma unroll
    for (int rr = 0; rr < 4; ++rr) {
        int ilocal = rr * 4 + il;
        const float* p0r = &p0s[ilocal * 64];
        float s = 0.f;
#pragma unroll 8
        for (int a = 0; a < 64; ++a) s = fmaf(p0r[a], Ms[a * 68 + c], s);
        size_t addr = ((size_t)bh * S_ + i0 + ilocal) * 64 + c;
        u16 hh, ll; splitf(s, hh, ll);
        qh[addr] = hh; ql[addr] = ll;
    }
}

// ---------------------------------------------------------------------------
// plain bf16 GEMM 64x64 (round-7 verbatim — PASSING)
// mode 0: out bf16 TRANSPOSED heads layout vT[(bh*64 + d)*S + s]   (v)
// mode 1: out fp32 natural                                          (final)
// ---------------------------------------------------------------------------
__global__ __launch_bounds__(256) void gemm_plain(
    const u16* __restrict__ Xb, const float* __restrict__ Wf,
    const float* __restrict__ bias, u16* __restrict__ outB,
    float* __restrict__ outF, int mode)
{
    const int K = 1024;
    __shared__ __align__(16) u16 Xs[64 * 40];
    __shared__ __align__(16) u16 Ws[64 * 40];

    const int tid = threadIdx.x;
    const int w = tid >> 6, lane = tid & 63;
    const int waveM = w & 1, waveN = w >> 1;
    const int quad = lane >> 4, l16 = lane & 15;
    const int bm = blockIdx.x, bn = blockIdx.y;
    const int lrow = tid >> 2, lkoff = (tid & 3) * 8;

    const u16* xg = Xb + (size_t)(bm * 64 + lrow) * K + lkoff;
    const float* wg = Wf + (size_t)(bn * 64 + lrow) * K + lkoff;

    f32x4 acc[2][2] = {};

    for (int k0 = 0; k0 < K; k0 += 32) {
        uint4 xv = *(const uint4*)(xg + k0);
        float4 w0 = *(const float4*)(wg + k0);
        float4 w1 = *(const float4*)(wg + k0 + 4);
        short8 wp;
        ((u16*)&wp)[0] = f2b(w0.x); ((u16*)&wp)[1] = f2b(w0.y);
        ((u16*)&wp)[2] = f2b(w0.z); ((u16*)&wp)[3] = f2b(w0.w);
        ((u16*)&wp)[4] = f2b(w1.x); ((u16*)&wp)[5] = f2b(w1.y);
        ((u16*)&wp)[6] = f2b(w1.z); ((u16*)&wp)[7] = f2b(w1.w);
        __syncthreads();
        *(uint4*)&Xs[lrow * 40 + lkoff] = xv;
        *(short8*)&Ws[lrow * 40 + lkoff] = wp;
        __syncthreads();

        short8 af[2], bf_[2];
#pragma unroll
        for (int mt = 0; mt < 2; ++mt)
            af[mt] = *(short8*)&Xs[(waveM * 32 + mt * 16 + l16) * 40 + quad * 8];
#pragma unroll
        for (int nt = 0; nt < 2; ++nt)
            bf_[nt] = *(short8*)&Ws[(waveN * 32 + nt * 16 + l16) * 40 + quad * 8];
#pragma unroll
        for (int mt = 0; mt < 2; ++mt)
#pragma unroll
            for (int nt = 0; nt < 2; ++nt)
                acc[mt][nt] = __builtin_amdgcn_mfma_f32_16x16x32_bf16(af[mt], bf_[nt], acc[mt][nt], 0, 0, 0);
    }

#pragma unroll
    for (int mt = 0; mt < 2; ++mt)
#pragma unroll
        for (int nt = 0; nt < 2; ++nt)
#pragma unroll
            for (int r = 0; r < 4; ++r) {
                int m = bm * 64 + waveM * 32 + mt * 16 + quad * 4 + r;
                int n = bn * 64 + waveN * 32 + nt * 16 + l16;
                float val = acc[mt][nt][r] + bias[n];
                if (mode == 0) {
                    int b = m >> 10, s = m & 1023, h = n >> 6, c = n & 63;
                    outB[((size_t)((b * H_ + h) * 64 + c)) * S_ + s] = f2b(val);
                } else {
                    outF[(size_t)m * 1024 + n] = val;
                }
            }
}

// ---------------------------------------------------------------------------
// FUSED logits+softmax+PV, v3: QK phase is BARRIER-FREE — p1 B-fragments
// loaded directly from global (16B/lane, 64B segments); no p1/v LDS at all.
// PV keeps only the Ps (P: C-layout -> A-layout) LDS round-trip.
// 512 thr; wave w: wg=w>>2 row-group (16 rows of 32), wj=w&3 j/d-quarter.
// ---------------------------------------------------------------------------
__global__ __launch_bounds__(512) void logits_softmax_pv(
    const u16* __restrict__ qh, const u16* __restrict__ ql,
    const u16* __restrict__ p1h, const u16* __restrict__ p1l,
    const u16* __restrict__ vT, float* __restrict__ attn,
    u16* __restrict__ values)
{
    int bh = blockIdx.y, i0 = blockIdx.x * 32;
    int b = bh >> 4, h = bh & 15;
    int tid = threadIdx.x, w = tid >> 6, lane = tid & 63;
    int quad = lane >> 4, l16 = lane & 15;
    int wg = w >> 2, wj = w & 3;

    __shared__ __align__(16) u16 qhs[32 * 72], qls[32 * 72];
    __shared__ __align__(16) u16 Ps[32 * 72];
    __shared__ float redm[4][32], reds[4][32];

    {   // stage q (32x64 hi/lo)
        int row = tid >> 4, c0 = (tid & 15) * 4;
        size_t g = ((size_t)bh * S_ + i0 + row) * 64 + c0;
        *(us4*)&qhs[row * 72 + c0] = *(const us4*)&qh[g];
        *(us4*)&qls[row * 72 + c0] = *(const us4*)&ql[g];
    }
    __syncthreads();

    short8 ah[2], al[2];
#pragma unroll
    for (int ch = 0; ch < 2; ++ch) {
        ah[ch] = *(short8*)&qhs[(wg * 16 + l16) * 72 + ch * 32 + quad * 8];
        al[ch] = *(short8*)&qls[(wg * 16 + l16) * 72 + ch * 32 + quad * 8];
    }

    // QK: direct-global p1 fragments. Lane reads row j = t*64 + wj*16 + l16,
    // cols ch*32 + quad*8 .. +7 (16 B contiguous).
    const u16* phb = p1h + ((size_t)bh * S_ + wj * 16 + l16) * 64 + quad * 8;
    const u16* plb = p1l + ((size_t)bh * S_ + wj * 16 + l16) * 64 + quad * 8;

    f32x4 L[16];
#pragma unroll 2
    for (int t = 0; t < 16; ++t) {
        const u16* ph = phb + (size_t)t * 64 * 64;
        const u16* pl = plb + (size_t)t * 64 * 64;
        short8 bh0 = *(const short8*)(ph);
        short8 bh1 = *(const short8*)(ph + 32);
        short8 bl0 = *(const short8*)(pl);
        short8 bl1 = *(const short8*)(pl + 32);
        f32x4 a = {};
        a = __builtin_amdgcn_mfma_f32_16x16x32_bf16(ah[0], bh0, a, 0, 0, 0);
        a = __builtin_amdgcn_mfma_f32_16x16x32_bf16(ah[1], bh1, a, 0, 0, 0);
        a = __builtin_amdgcn_mfma_f32_16x16x32_bf16(ah[0], bl0, a, 0, 0, 0);
        a = __builtin_amdgcn_mfma_f32_16x16x32_bf16(ah[1], bl1, a, 0, 0, 0);
        a = __builtin_amdgcn_mfma_f32_16x16x32_bf16(al[0], bh0, a, 0, 0, 0);
        a = __builtin_amdgcn_mfma_f32_16x16x32_bf16(al[1], bh1, a, 0, 0, 0);
        L[t] = a;
    }

    // softmax: lane holds rows wg*16 + quad*4 + r, cols {64t + 16wj + l16}
    float mrow[4], srow[4];
#pragma unroll
    for (int r = 0; r < 4; ++r) {
        float m = L[0][r];
#pragma unroll
        for (int t = 1; t < 16; ++t) m = fmaxf(m, L[t][r]);
#pragma unroll
        for (int off = 1; off < 16; off <<= 1) m = fmaxf(m, __shfl_xor(m, off, 64));
        mrow[r] = m;
    }
    if (l16 == 0)
#pragma unroll
        for (int r = 0; r < 4; ++r) redm[wj][wg * 16 + quad * 4 + r] = mrow[r];
    __syncthreads();
#pragma unroll
    for (int r = 0; r < 4; ++r) {
        int rowg = wg * 16 + quad * 4 + r;
        float m = fmaxf(fmaxf(redm[0][rowg], redm[1][rowg]),
                        fmaxf(redm[2][rowg], redm[3][rowg]));
        float s = 0.f;
#pragma unroll
        for (int t = 0; t < 16; ++t) { L[t][r] = __expf(L[t][r] - m); s += L[t][r]; }
#pragma unroll
        for (int off = 1; off < 16; off <<= 1) s += __shfl_xor(s, off, 64);
        srow[r] = s;
    }
    if (l16 == 0)
#pragma unroll
        for (int r = 0; r < 4; ++r) reds[wj][wg * 16 + quad * 4 + r] = srow[r];
    __syncthreads();
#pragma unroll
    for (int r = 0; r < 4; ++r) {
        int rowg = wg * 16 + quad * 4 + r;
        float inv = 1.0f / (reds[0][rowg] + reds[1][rowg] + reds[2][rowg] + reds[3][rowg]);
        float* arow = attn + ((size_t)bh * S_ + i0 + rowg) * S_;
#pragma unroll
        for (int t = 0; t < 16; ++t) {
            float p = L[t][r] * inv;
            L[t][r] = p;                          // keep normalized P for PV
            __builtin_nontemporal_store(p, &arow[t * 64 + wj * 16 + l16]);
        }
    }

    // ---- PV: values[i][d] = sum_j P[i][j] * v[j][d] ----
    // v B-fragment direct from vT: row d = wj*16 + l16, k=j contiguous.
    const u16* vb = vT + ((size_t)(bh * 64 + wj * 16 + l16)) * S_ + quad * 8;

    f32x4 acc_pv = {};
    for (int t = 0; t < 16; ++t) {
        short8 bf0 = *(const short8*)(vb + t * 64);
        short8 bf1 = *(const short8*)(vb + t * 64 + 32);
        __syncthreads();
        // P tile (32 x 64) regs -> LDS (stride 72)
#pragma unroll
        for (int r = 0; r < 4; ++r)
            Ps[(wg * 16 + quad * 4 + r) * 72 + wj * 16 + l16] = f2b(L[t][r]);
        __syncthreads();
        short8 af0 = *(short8*)&Ps[(wg * 16 + l16) * 72 + quad * 8];
        short8 af1 = *(short8*)&Ps[(wg * 16 + l16) * 72 + 32 + quad * 8];
        acc_pv = __builtin_amdgcn_mfma_f32_16x16x32_bf16(af0, bf0, acc_pv, 0, 0, 0);
        acc_pv = __builtin_amdgcn_mfma_f32_16x16x32_bf16(af1, bf1, acc_pv, 0, 0, 0);
    }
#pragma unroll
    for (int r = 0; r < 4; ++r) {
        int i = i0 + wg * 16 + quad * 4 + r;
        int d = wj * 16 + l16;
        values[((size_t)(b * S_ + i)) * E_ + h * 64 + d] = f2b(acc_pv[r]);
    }
}

extern "C" void kernel_launch(void* const* d_in, const int* in_sizes, int n_in,
                              void* d_out, int out_size, void* d_ws, size_t ws_size,
                              hipStream_t stream)
{
    const float* x  = (const float*)d_in[0];
    const float* W0 = (const float*)d_in[1];
    const float* b0 = (const float*)d_in[2];
    const float* W1 = (const float*)d_in[3];
    const float* b1 = (const float*)d_in[4];
    const float* W2 = (const float*)d_in[5];
    const float* b2 = (const float*)d_in[6];
    const float* Wv = (const float*)d_in[7];
    const float* bv = (const float*)d_in[8];
    const float* Wo = (const float*)d_in[9];
    const float* bo = (const float*)d_in[10];
    const float* A  = (const float*)d_in[11];

    float* out  = (float*)d_out;
    float* attn = out + (size_t)B_ * S_ * E_;

    // workspace (~88 MB; harness fill counters show d_ws >= 1 GB)
    u16* xh  = (u16*)d_ws;                  // 8 MB
    u16* xl  = xh + 4194304;                // 8 MB
    u16* w0h = xl + 4194304;                // 2 MB
    u16* w0l = w0h + 1048576;
    u16* w1h = w0l + 1048576;
    u16* w1l = w1h + 1048576;
    u16* p1h = w1l + 1048576;               // 8 MB
    u16* p1l = p1h + 4194304;               // 8 MB
    u16* qh  = p1l + 4194304;               // 8 MB
    u16* ql  = qh + 4194304;                // 8 MB
    u16* vT  = ql + 4194304;                // 8 MB (heads-transposed v)
    u16* values = vT + 4194304;             // 8 MB (bf16 natural)
    float* p0F  = (float*)(values + 4194304);  // 16 MB fp32 heads
    float* xsum = p0F + 4194304;            // 4096
    float* t2n  = xsum + 4096;              // 4096
    float* Mm   = t2n + 4096;               // 262144

    split_pair<<<4096, 256, 0, stream>>>(x, xh, xl, 1048576);
    split_pair<<<1024, 256, 0, stream>>>(W0, w0h, w0l, 262144);
    split_pair<<<1024, 256, 0, stream>>>(W1, w1h, w1l, 262144);
    reduce_xsum<<<dim3(4, 4), 256, 0, stream>>>(x, xsum);
    compute_t2k<<<dim3(16, 4), 256, 0, stream>>>(W2, b2, xsum, t2n);
    compute_M<<<BH_, 256, 0, stream>>>(A, t2n, Mm);

    dim3 gs(32, 16);
    gemm_split128<<<gs, 256, 0, stream>>>(xh, xl, w0h, w0l, b0, p0F, nullptr, nullptr, 0); // p0
    gemm_split128<<<gs, 256, 0, stream>>>(xh, xl, w1h, w1l, b1, nullptr, p1h, p1l, 1);     // p1

    dim3 gp(64, 16);
    gemm_plain<<<gp, 256, 0, stream>>>(xh, Wv, bv, vT, nullptr, 0);                        // vT

    compute_q<<<dim3(64, 64), 256, 0, stream>>>(p0F, Mm, qh, ql);

    logits_softmax_pv<<<dim3(32, 64), 512, 0, stream>>>(qh, ql, p1h, p1l, vT, attn, values);

    gemm_plain<<<gp, 256, 0, stream>>>(values, Wo, bo, nullptr, out, 1);
}

// Round 10
// 710.527 us; speedup vs baseline: 1.5056x; 1.5056x over previous
//
#include <hip/hip_runtime.h>
#include <hip/hip_bf16.h>
#include <cstddef>

#define B_ 4
#define S_ 1024
#define E_ 1024
#define H_ 16
#define D_ 64
#define BH_ (B_*H_)

typedef __attribute__((ext_vector_type(8))) short short8;    // 8 bf16
typedef __attribute__((ext_vector_type(4))) float f32x4;
typedef __attribute__((ext_vector_type(4))) unsigned short us4;
typedef unsigned short u16;

__device__ inline u16 f2b(float x) {
    return __builtin_bit_cast(u16, __float2bfloat16(x));
}
__device__ inline float b2f(u16 u) {
    return __bfloat162float(__builtin_bit_cast(__hip_bfloat16, u));
}
__device__ inline void splitf(float x, u16& h, u16& l) {
    h = f2b(x); l = f2b(x - b2f(h));
}

// ---------------------------------------------------------------------------
// split fp32 array into hi/lo bf16 arrays (n4 = n/4)
// ---------------------------------------------------------------------------
__global__ __launch_bounds__(256) void split_pair(
    const float* __restrict__ in, u16* __restrict__ oh, u16* __restrict__ ol, int n4)
{
    int i = blockIdx.x * 256 + threadIdx.x;
    if (i >= n4) return;
    float4 v = ((const float4*)in)[i];
    us4 h, l;
    splitf(v.x, ((u16*)&h)[0], ((u16*)&l)[0]);
    splitf(v.y, ((u16*)&h)[1], ((u16*)&l)[1]);
    splitf(v.z, ((u16*)&h)[2], ((u16*)&l)[2]);
    splitf(v.w, ((u16*)&h)[3], ((u16*)&l)[3]);
    ((us4*)oh)[i] = h;
    ((us4*)ol)[i] = l;
}

// xsum[b][k] = sum_s x[b,s,k]
__global__ __launch_bounds__(256) void reduce_xsum(
    const float* __restrict__ x, float* __restrict__ xsum)
{
    int b = blockIdx.y;
    int k = blockIdx.x * 256 + threadIdx.x;
    float s = 0.f;
    const float* base = x + (size_t)b * S_ * E_ + k;
    for (int j = 0; j < S_; ++j) s += base[(size_t)j * E_];
    xsum[b * E_ + k] = s;
}

// t2n[b][n] = dot(W2[n], xsum[b]) + S*b2[n]
__global__ __launch_bounds__(256) void compute_t2k(
    const float* __restrict__ W2, const float* __restrict__ b2,
    const float* __restrict__ xsum, float* __restrict__ t2n)
{
    int b = blockIdx.y, n0 = blockIdx.x * 64;
    int w = threadIdx.x >> 6, lane = threadIdx.x & 63;
    const float* xs = xsum + b * E_;
    for (int nn = w; nn < 64; nn += 4) {
        int n = n0 + nn;
        const float* wr = W2 + (size_t)n * E_;
        float s = 0.f;
#pragma unroll
        for (int t = 0; t < 16; ++t) s = fmaf(wr[t * 64 + lane], xs[t * 64 + lane], s);
#pragma unroll
        for (int off = 1; off < 64; off <<= 1) s += __shfl_xor(s, off, 64);
        if (lane == 0) t2n[b * E_ + n] = s + 1024.0f * b2[n];
    }
}

// M[bh][a][c] = (1/8) * sum_d A[a][c][d] * t2[bh][d]
__global__ void compute_M(const float* __restrict__ A, const float* __restrict__ t2n,
                          float* __restrict__ Mout)
{
    int bh = blockIdx.x, b = bh >> 4, h = bh & 15;
    __shared__ float ts[64];
    if (threadIdx.x < 64) ts[threadIdx.x] = t2n[b * E_ + h * 64 + threadIdx.x];
    __syncthreads();
    int c = threadIdx.x & 63;
    int a0 = (threadIdx.x >> 6) * 16;
    for (int a = a0; a < a0 + 16; ++a) {
        float s = 0.f;
        const float* Ap = A + ((size_t)a * 64 + c) * 64;
#pragma unroll 8
        for (int d = 0; d < 64; ++d) s = fmaf(Ap[d], ts[d], s);
        Mout[((size_t)bh * 64 + a) * 64 + c] = s * 0.125f;
    }
}

// ---------------------------------------------------------------------------
// split-bf16 GEMM, 128x64 tile (round-7 verbatim — PASSING)
// ---------------------------------------------------------------------------
__global__ __launch_bounds__(256) void gemm_split128(
    const u16* __restrict__ Xh, const u16* __restrict__ Xl,
    const u16* __restrict__ Wh, const u16* __restrict__ Wl,
    const float* __restrict__ bias, float* __restrict__ outF,
    u16* __restrict__ oh, u16* __restrict__ ol, int mode)
{
    const int K = 1024;
    __shared__ __align__(16) u16 Xs_h[128 * 40];
    __shared__ __align__(16) u16 Xs_l[128 * 40];
    __shared__ __align__(16) u16 Ws_h[64 * 40];
    __shared__ __align__(16) u16 Ws_l[64 * 40];

    const int tid = threadIdx.x;
    const int w = tid >> 6, lane = tid & 63;
    const int waveM = w & 1, waveN = w >> 1;
    const int quad = lane >> 4, l16 = lane & 15;
    const int bm = blockIdx.x, bn = blockIdx.y;

    const int xrow = tid >> 1, xko = (tid & 1) * 16;
    const int wrow = tid >> 2, wko = (tid & 3) * 8;

    const u16* xh_g = Xh + (size_t)(bm * 128 + xrow) * K + xko;
    const u16* xl_g = Xl + (size_t)(bm * 128 + xrow) * K + xko;
    const u16* wh_g = Wh + (size_t)(bn * 64 + wrow) * K + wko;
    const u16* wl_g = Wl + (size_t)(bn * 64 + wrow) * K + wko;

    f32x4 acc[4][2] = {};

    for (int k0 = 0; k0 < K; k0 += 32) {
        uint4 xa = *(const uint4*)(xh_g + k0);
        uint4 xb = *(const uint4*)(xh_g + k0 + 8);
        uint4 xc = *(const uint4*)(xl_g + k0);
        uint4 xd = *(const uint4*)(xl_g + k0 + 8);
        uint4 wa = *(const uint4*)(wh_g + k0);
        uint4 wc = *(const uint4*)(wl_g + k0);
        __syncthreads();
        *(uint4*)&Xs_h[xrow * 40 + xko]     = xa;
        *(uint4*)&Xs_h[xrow * 40 + xko + 8] = xb;
        *(uint4*)&Xs_l[xrow * 40 + xko]     = xc;
        *(uint4*)&Xs_l[xrow * 40 + xko + 8] = xd;
        *(uint4*)&Ws_h[wrow * 40 + wko] = wa;
        *(uint4*)&Ws_l[wrow * 40 + wko] = wc;
        __syncthreads();

        short8 ah[4], al[4], bh_[2], bl_[2];
#pragma unroll
        for (int mt = 0; mt < 4; ++mt) {
            int r = (waveM * 64 + mt * 16 + l16) * 40 + quad * 8;
            ah[mt] = *(short8*)&Xs_h[r];
            al[mt] = *(short8*)&Xs_l[r];
        }
#pragma unroll
        for (int nt = 0; nt < 2; ++nt) {
            int r = (waveN * 32 + nt * 16 + l16) * 40 + quad * 8;
            bh_[nt] = *(short8*)&Ws_h[r];
            bl_[nt] = *(short8*)&Ws_l[r];
        }
#pragma unroll
        for (int mt = 0; mt < 4; ++mt)
#pragma unroll
            for (int nt = 0; nt < 2; ++nt) {
                acc[mt][nt] = __builtin_amdgcn_mfma_f32_16x16x32_bf16(ah[mt], bh_[nt], acc[mt][nt], 0, 0, 0);
                acc[mt][nt] = __builtin_amdgcn_mfma_f32_16x16x32_bf16(ah[mt], bl_[nt], acc[mt][nt], 0, 0, 0);
                acc[mt][nt] = __builtin_amdgcn_mfma_f32_16x16x32_bf16(al[mt], bh_[nt], acc[mt][nt], 0, 0, 0);
            }
    }

#pragma unroll
    for (int mt = 0; mt < 4; ++mt)
#pragma unroll
        for (int nt = 0; nt < 2; ++nt)
#pragma unroll
            for (int r = 0; r < 4; ++r) {
                int m = bm * 128 + waveM * 64 + mt * 16 + quad * 4 + r;
                int n = bn * 64 + waveN * 32 + nt * 16 + l16;
                float val = acc[mt][nt][r] + bias[n];
                int b = m >> 10, s = m & 1023, h = n >> 6, c = n & 63;
                size_t addr = ((size_t)(b * H_ + h) * S_ + s) * 64 + c;
                if (mode == 0) {
                    outF[addr] = val;
                } else {
                    u16 hh, ll; splitf(val, hh, ll);
                    oh[addr] = hh; ol[addr] = ll;
                }
            }
}

// q[bh][i][c] = sum_a p0[bh][i][a] * M[bh][a][c]; write hi/lo bf16
__global__ __launch_bounds__(256) void compute_q(
    const float* __restrict__ p0, const float* __restrict__ Min,
    u16* __restrict__ qh, u16* __restrict__ ql)
{
    int bh = blockIdx.y, i0 = blockIdx.x * 16;
    __shared__ float Ms[64 * 68];
    __shared__ float p0s[16 * 64];
    const float* base = p0 + ((size_t)bh * S_ + i0) * 64;
    for (int t = threadIdx.x; t < 4096; t += 256)
        Ms[(t >> 6) * 68 + (t & 63)] = Min[(size_t)bh * 4096 + t];
    for (int t = threadIdx.x; t < 1024; t += 256) p0s[t] = base[t];
    __syncthreads();
    int c = threadIdx.x & 63, il = threadIdx.x >> 6;
#pragma unroll
    for (int rr = 0; rr < 4; ++rr) {
        int ilocal = rr * 4 + il;
        const float* p0r = &p0s[ilocal * 64];
        float s = 0.f;
#pragma unroll 8
        for (int a = 0; a < 64; ++a) s = fmaf(p0r[a], Ms[a * 68 + c], s);
        size_t addr = ((size_t)bh * S_ + i0 + ilocal) * 64 + c;
        u16 hh, ll; splitf(s, hh, ll);
        qh[addr] = hh; ql[addr] = ll;
    }
}

// ---------------------------------------------------------------------------
// plain bf16 GEMM 64x64 (round-7 verbatim — PASSING)
// mode 0: out bf16 TRANSPOSED heads layout vT[(bh*64 + d)*S + s]   (v)
// mode 1: out fp32 natural                                          (final)
// ---------------------------------------------------------------------------
__global__ __launch_bounds__(256) void gemm_plain(
    const u16* __restrict__ Xb, const float* __restrict__ Wf,
    const float* __restrict__ bias, u16* __restrict__ outB,
    float* __restrict__ outF, int mode)
{
    const int K = 1024;
    __shared__ __align__(16) u16 Xs[64 * 40];
    __shared__ __align__(16) u16 Ws[64 * 40];

    const int tid = threadIdx.x;
    const int w = tid >> 6, lane = tid & 63;
    const int waveM = w & 1, waveN = w >> 1;
    const int quad = lane >> 4, l16 = lane & 15;
    const int bm = blockIdx.x, bn = blockIdx.y;
    const int lrow = tid >> 2, lkoff = (tid & 3) * 8;

    const u16* xg = Xb + (size_t)(bm * 64 + lrow) * K + lkoff;
    const float* wg = Wf + (size_t)(bn * 64 + lrow) * K + lkoff;

    f32x4 acc[2][2] = {};

    for (int k0 = 0; k0 < K; k0 += 32) {
        uint4 xv = *(const uint4*)(xg + k0);
        float4 w0 = *(const float4*)(wg + k0);
        float4 w1 = *(const float4*)(wg + k0 + 4);
        short8 wp;
        ((u16*)&wp)[0] = f2b(w0.x); ((u16*)&wp)[1] = f2b(w0.y);
        ((u16*)&wp)[2] = f2b(w0.z); ((u16*)&wp)[3] = f2b(w0.w);
        ((u16*)&wp)[4] = f2b(w1.x); ((u16*)&wp)[5] = f2b(w1.y);
        ((u16*)&wp)[6] = f2b(w1.z); ((u16*)&wp)[7] = f2b(w1.w);
        __syncthreads();
        *(uint4*)&Xs[lrow * 40 + lkoff] = xv;
        *(short8*)&Ws[lrow * 40 + lkoff] = wp;
        __syncthreads();

        short8 af[2], bf_[2];
#pragma unroll
        for (int mt = 0; mt < 2; ++mt)
            af[mt] = *(short8*)&Xs[(waveM * 32 + mt * 16 + l16) * 40 + quad * 8];
#pragma unroll
        for (int nt = 0; nt < 2; ++nt)
            bf_[nt] = *(short8*)&Ws[(waveN * 32 + nt * 16 + l16) * 40 + quad * 8];
#pragma unroll
        for (int mt = 0; mt < 2; ++mt)
#pragma unroll
            for (int nt = 0; nt < 2; ++nt)
                acc[mt][nt] = __builtin_amdgcn_mfma_f32_16x16x32_bf16(af[mt], bf_[nt], acc[mt][nt], 0, 0, 0);
    }

#pragma unroll
    for (int mt = 0; mt < 2; ++mt)
#pragma unroll
        for (int nt = 0; nt < 2; ++nt)
#pragma unroll
            for (int r = 0; r < 4; ++r) {
                int m = bm * 64 + waveM * 32 + mt * 16 + quad * 4 + r;
                int n = bn * 64 + waveN * 32 + nt * 16 + l16;
                float val = acc[mt][nt][r] + bias[n];
                if (mode == 0) {
                    int b = m >> 10, s = m & 1023, h = n >> 6, c = n & 63;
                    outB[((size_t)((b * H_ + h) * 64 + c)) * S_ + s] = f2b(val);
                } else {
                    outF[(size_t)m * 1024 + n] = val;
                }
            }
}

// ---------------------------------------------------------------------------
// FUSED logits+softmax+PV, v4: r8 structure (LDS-staged QK — pacing keeps L2
// hot, r9 lesson) + QK double-buffered LDS with ONE barrier per tile and
// depth-2 register prefetch. PV phase identical to r8.
// 512 thr; wave w: wg=w>>2 row-group (16 rows of 32), wj=w&3 j/d-quarter.
// ---------------------------------------------------------------------------
__global__ __launch_bounds__(512) void logits_softmax_pv(
    const u16* __restrict__ qh, const u16* __restrict__ ql,
    const u16* __restrict__ p1h, const u16* __restrict__ p1l,
    const u16* __restrict__ vT, float* __restrict__ attn,
    u16* __restrict__ values)
{
    int bh = blockIdx.y, i0 = blockIdx.x * 32;
    int b = bh >> 4, h = bh & 15;
    int tid = threadIdx.x, w = tid >> 6, lane = tid & 63;
    int quad = lane >> 4, l16 = lane & 15;
    int wg = w >> 2, wj = w & 3;

    __shared__ __align__(16) u16 qhs[32 * 72], qls[32 * 72];
    __shared__ __align__(16) u16 p1hs[2][64 * 72], p1ls[2][64 * 72];
    __shared__ __align__(16) u16 Ps[32 * 72];
    __shared__ __align__(16) u16 vs_[64 * 72];
    __shared__ float redm[4][32], reds[4][32];

    {   // stage q (32x64 hi/lo)
        int row = tid >> 4, c0 = (tid & 15) * 4;
        size_t g = ((size_t)bh * S_ + i0 + row) * 64 + c0;
        *(us4*)&qhs[row * 72 + c0] = *(const us4*)&qh[g];
        *(us4*)&qls[row * 72 + c0] = *(const us4*)&ql[g];
    }

    // p1 staging: thread covers (row jl, 8 cols) — tile stride 4096 elems
    const int jl = tid >> 3, c0s = (tid & 7) * 8;
    const size_t gp = ((size_t)bh * S_ + jl) * 64 + c0s;

    // tile 0 -> buf0; tile 1 into regs (depth-2 pipeline)
    uint4 rha = *(const uint4*)&p1h[gp];
    uint4 rla = *(const uint4*)&p1l[gp];
    *(uint4*)&p1hs[0][jl * 72 + c0s] = rha;
    *(uint4*)&p1ls[0][jl * 72 + c0s] = rla;
    uint4 rh1 = *(const uint4*)&p1h[gp + 4096];
    uint4 rl1 = *(const uint4*)&p1l[gp + 4096];
    __syncthreads();    // q + buf0 visible

    short8 ah[2], al[2];
#pragma unroll
    for (int ch = 0; ch < 2; ++ch) {
        ah[ch] = *(short8*)&qhs[(wg * 16 + l16) * 72 + ch * 32 + quad * 8];
        al[ch] = *(short8*)&qls[(wg * 16 + l16) * 72 + ch * 32 + quad * 8];
    }

    f32x4 L[16];
    for (int t = 0; t < 16; ++t) {
        int cur = t & 1;
        uint4 rh2, rl2;
        if (t < 14) {                       // issue t+2 load (2-tile latency window)
            size_t gn = gp + (size_t)(t + 2) * 4096;
            rh2 = *(const uint4*)&p1h[gn];
            rl2 = *(const uint4*)&p1l[gn];
        }
        int jr = wj * 16 + l16;
        const u16* Hb = &p1hs[cur][jr * 72];
        const u16* Lb = &p1ls[cur][jr * 72];
        short8 bh0 = *(const short8*)(Hb + quad * 8);
        short8 bh1 = *(const short8*)(Hb + 32 + quad * 8);
        short8 bl0 = *(const short8*)(Lb + quad * 8);
        short8 bl1 = *(const short8*)(Lb + 32 + quad * 8);
        f32x4 a = {};
        a = __builtin_amdgcn_mfma_f32_16x16x32_bf16(ah[0], bh0, a, 0, 0, 0);
        a = __builtin_amdgcn_mfma_f32_16x16x32_bf16(ah[1], bh1, a, 0, 0, 0);
        a = __builtin_amdgcn_mfma_f32_16x16x32_bf16(ah[0], bl0, a, 0, 0, 0);
        a = __builtin_amdgcn_mfma_f32_16x16x32_bf16(ah[1], bl1, a, 0, 0, 0);
        a = __builtin_amdgcn_mfma_f32_16x16x32_bf16(al[0], bh0, a, 0, 0, 0);
        a = __builtin_amdgcn_mfma_f32_16x16x32_bf16(al[1], bh1, a, 0, 0, 0);
        L[t] = a;
        if (t < 15) {                       // stage t+1 into the other buffer
            *(uint4*)&p1hs[1 - cur][jl * 72 + c0s] = rh1;
            *(uint4*)&p1ls[1 - cur][jl * 72 + c0s] = rl1;
            if (t < 14) { rh1 = rh2; rl1 = rl2; }
            __syncthreads();                // single barrier per tile
        }
    }

    // softmax: lane holds rows wg*16 + quad*4 + r, cols {64t + 16wj + l16}
    float mrow[4], srow[4];
#pragma unroll
    for (int r = 0; r < 4; ++r) {
        float m = L[0][r];
#pragma unroll
        for (int t = 1; t < 16; ++t) m = fmaxf(m, L[t][r]);
#pragma unroll
        for (int off = 1; off < 16; off <<= 1) m = fmaxf(m, __shfl_xor(m, off, 64));
        mrow[r] = m;
    }
    if (l16 == 0)
#pragma unroll
        for (int r = 0; r < 4; ++r) redm[wj][wg * 16 + quad * 4 + r] = mrow[r];
    __syncthreads();
#pragma unroll
    for (int r = 0; r < 4; ++r) {
        int rowg = wg * 16 + quad * 4 + r;
        float m = fmaxf(fmaxf(redm[0][rowg], redm[1][rowg]),
                        fmaxf(redm[2][rowg], redm[3][rowg]));
        float s = 0.f;
#pragma unroll
        for (int t = 0; t < 16; ++t) { L[t][r] = __expf(L[t][r] - m); s += L[t][r]; }
#pragma unroll
        for (int off = 1; off < 16; off <<= 1) s += __shfl_xor(s, off, 64);
        srow[r] = s;
    }
    if (l16 == 0)
#pragma unroll
        for (int r = 0; r < 4; ++r) reds[wj][wg * 16 + quad * 4 + r] = srow[r];
    __syncthreads();
#pragma unroll
    for (int r = 0; r < 4; ++r) {
        int rowg = wg * 16 + quad * 4 + r;
        float inv = 1.0f / (reds[0][rowg] + reds[1][rowg] + reds[2][rowg] + reds[3][rowg]);
        float* arow = attn + ((size_t)bh * S_ + i0 + rowg) * S_;
#pragma unroll
        for (int t = 0; t < 16; ++t) {
            float p = L[t][r] * inv;
            L[t][r] = p;                          // keep normalized P for PV
            __builtin_nontemporal_store(p, &arow[t * 64 + wj * 16 + l16]);
        }
    }

    // ---- PV: values[i][d] = sum_j P[i][j] * v[j][d] ---- (r8 verbatim)
    const int dv = tid >> 3, jc = (tid & 7) * 8;
    size_t gv = ((size_t)(bh * 64 + dv)) * S_ + jc;
    uint4 rv = *(const uint4*)&vT[gv];

    f32x4 acc_pv = {};
    for (int t = 0; t < 16; ++t) {
        __syncthreads();
        // P tile (32 x 64) regs -> LDS (stride 72)
#pragma unroll
        for (int r = 0; r < 4; ++r)
            Ps[(wg * 16 + quad * 4 + r) * 72 + wj * 16 + l16] = f2b(L[t][r]);
        *(uint4*)&vs_[dv * 72 + jc] = rv;
        __syncthreads();
        if (t < 15) rv = *(const uint4*)&vT[gv + (size_t)(t + 1) * 64];
        int d = wj * 16 + l16;
#pragma unroll
        for (int cc = 0; cc < 64; cc += 32) {
            short8 af = *(short8*)&Ps[(wg * 16 + l16) * 72 + cc + quad * 8];
            short8 bf = *(short8*)&vs_[d * 72 + cc + quad * 8];
            acc_pv = __builtin_amdgcn_mfma_f32_16x16x32_bf16(af, bf, acc_pv, 0, 0, 0);
        }
    }
#pragma unroll
    for (int r = 0; r < 4; ++r) {
        int i = i0 + wg * 16 + quad * 4 + r;
        int d = wj * 16 + l16;
        values[((size_t)(b * S_ + i)) * E_ + h * 64 + d] = f2b(acc_pv[r]);
    }
}

extern "C" void kernel_launch(void* const* d_in, const int* in_sizes, int n_in,
                              void* d_out, int out_size, void* d_ws, size_t ws_size,
                              hipStream_t stream)
{
    const float* x  = (const float*)d_in[0];
    const float* W0 = (const float*)d_in[1];
    const float* b0 = (const float*)d_in[2];
    const float* W1 = (const float*)d_in[3];
    const float* b1 = (const float*)d_in[4];
    const float* W2 = (const float*)d_in[5];
    const float* b2 = (const float*)d_in[6];
    const float* Wv = (const float*)d_in[7];
    const float* bv = (const float*)d_in[8];
    const float* Wo = (const float*)d_in[9];
    const float* bo = (const float*)d_in[10];
    const float* A  = (const float*)d_in[11];

    float* out  = (float*)d_out;
    float* attn = out + (size_t)B_ * S_ * E_;

    // workspace (~88 MB; harness fill counters show d_ws >= 1 GB)
    u16* xh  = (u16*)d_ws;                  // 8 MB
    u16* xl  = xh + 4194304;                // 8 MB
    u16* w0h = xl + 4194304;                // 2 MB
    u16* w0l = w0h + 1048576;
    u16* w1h = w0l + 1048576;
    u16* w1l = w1h + 1048576;
    u16* p1h = w1l + 1048576;               // 8 MB
    u16* p1l = p1h + 4194304;               // 8 MB
    u16* qh  = p1l + 4194304;               // 8 MB
    u16* ql  = qh + 4194304;                // 8 MB
    u16* vT  = ql + 4194304;                // 8 MB (heads-transposed v)
    u16* values = vT + 4194304;             // 8 MB (bf16 natural)
    float* p0F  = (float*)(values + 4194304);  // 16 MB fp32 heads
    float* xsum = p0F + 4194304;            // 4096
    float* t2n  = xsum + 4096;              // 4096
    float* Mm   = t2n + 4096;               // 262144

    split_pair<<<4096, 256, 0, stream>>>(x, xh, xl, 1048576);
    split_pair<<<1024, 256, 0, stream>>>(W0, w0h, w0l, 262144);
    split_pair<<<1024, 256, 0, stream>>>(W1, w1h, w1l, 262144);
    reduce_xsum<<<dim3(4, 4), 256, 0, stream>>>(x, xsum);
    compute_t2k<<<dim3(16, 4), 256, 0, stream>>>(W2, b2, xsum, t2n);
    compute_M<<<BH_, 256, 0, stream>>>(A, t2n, Mm);

    dim3 gs(32, 16);
    gemm_split128<<<gs, 256, 0, stream>>>(xh, xl, w0h, w0l, b0, p0F, nullptr, nullptr, 0); // p0
    gemm_split128<<<gs, 256, 0, stream>>>(xh, xl, w1h, w1l, b1, nullptr, p1h, p1l, 1);     // p1

    dim3 gp(64, 16);
    gemm_plain<<<gp, 256, 0, stream>>>(xh, Wv, bv, vT, nullptr, 0);                        // vT

    compute_q<<<dim3(64, 64), 256, 0, stream>>>(p0F, Mm, qh, ql);

    logits_softmax_pv<<<dim3(32, 64), 512, 0, stream>>>(qh, ql, p1h, p1l, vT, attn, values);

    gemm_plain<<<gp, 256, 0, stream>>>(values, Wo, bo, nullptr, out, 1);
}

// Round 11
// 681.784 us; speedup vs baseline: 1.5691x; 1.0422x over previous
//
#include <hip/hip_runtime.h>
#include <hip/hip_bf16.h>
#include <cstddef>

#define B_ 4
#define S_ 1024
#define E_ 1024
#define H_ 16
#define D_ 64
#define BH_ (B_*H_)

typedef __attribute__((ext_vector_type(8))) short short8;    // 8 bf16
typedef __attribute__((ext_vector_type(4))) float f32x4;
typedef __attribute__((ext_vector_type(4))) unsigned short us4;
typedef unsigned short u16;

__device__ inline u16 f2b(float x) {
    return __builtin_bit_cast(u16, __float2bfloat16(x));
}
__device__ inline float b2f(u16 u) {
    return __bfloat162float(__builtin_bit_cast(__hip_bfloat16, u));
}
__device__ inline void splitf(float x, u16& h, u16& l) {
    h = f2b(x); l = f2b(x - b2f(h));
}

// ---------------------------------------------------------------------------
// split fp32 array into hi/lo bf16 arrays (n4 = n/4)
// ---------------------------------------------------------------------------
__global__ __launch_bounds__(256) void split_pair(
    const float* __restrict__ in, u16* __restrict__ oh, u16* __restrict__ ol, int n4)
{
    int i = blockIdx.x * 256 + threadIdx.x;
    if (i >= n4) return;
    float4 v = ((const float4*)in)[i];
    us4 h, l;
    splitf(v.x, ((u16*)&h)[0], ((u16*)&l)[0]);
    splitf(v.y, ((u16*)&h)[1], ((u16*)&l)[1]);
    splitf(v.z, ((u16*)&h)[2], ((u16*)&l)[2]);
    splitf(v.w, ((u16*)&h)[3], ((u16*)&l)[3]);
    ((us4*)oh)[i] = h;
    ((us4*)ol)[i] = l;
}

// xsum[b][k] = sum_s x[b,s,k]
__global__ __launch_bounds__(256) void reduce_xsum(
    const float* __restrict__ x, float* __restrict__ xsum)
{
    int b = blockIdx.y;
    int k = blockIdx.x * 256 + threadIdx.x;
    float s = 0.f;
    const float* base = x + (size_t)b * S_ * E_ + k;
    for (int j = 0; j < S_; ++j) s += base[(size_t)j * E_];
    xsum[b * E_ + k] = s;
}

// t2n[b][n] = dot(W2[n], xsum[b]) + S*b2[n]
__global__ __launch_bounds__(256) void compute_t2k(
    const float* __restrict__ W2, const float* __restrict__ b2,
    const float* __restrict__ xsum, float* __restrict__ t2n)
{
    int b = blockIdx.y, n0 = blockIdx.x * 64;
    int w = threadIdx.x >> 6, lane = threadIdx.x & 63;
    const float* xs = xsum + b * E_;
    for (int nn = w; nn < 64; nn += 4) {
        int n = n0 + nn;
        const float* wr = W2 + (size_t)n * E_;
        float s = 0.f;
#pragma unroll
        for (int t = 0; t < 16; ++t) s = fmaf(wr[t * 64 + lane], xs[t * 64 + lane], s);
#pragma unroll
        for (int off = 1; off < 64; off <<= 1) s += __shfl_xor(s, off, 64);
        if (lane == 0) t2n[b * E_ + n] = s + 1024.0f * b2[n];
    }
}

// MT (transposed M) hi/lo bf16: MT[bh][c*64+a] = (1/8)*sum_d A[a][c][d]*t2[bh][d]
__global__ void compute_M(const float* __restrict__ A, const float* __restrict__ t2n,
                          u16* __restrict__ MTh, u16* __restrict__ MTl)
{
    int bh = blockIdx.x, b = bh >> 4, h = bh & 15;
    __shared__ float ts[64];
    if (threadIdx.x < 64) ts[threadIdx.x] = t2n[b * E_ + h * 64 + threadIdx.x];
    __syncthreads();
    int c = threadIdx.x & 63;
    int a0 = (threadIdx.x >> 6) * 16;
    for (int a = a0; a < a0 + 16; ++a) {
        float s = 0.f;
        const float* Ap = A + ((size_t)a * 64 + c) * 64;
#pragma unroll 8
        for (int d = 0; d < 64; ++d) s = fmaf(Ap[d], ts[d], s);
        u16 hh, ll; splitf(s * 0.125f, hh, ll);
        MTh[(size_t)bh * 4096 + c * 64 + a] = hh;
        MTl[(size_t)bh * 4096 + c * 64 + a] = ll;
    }
}

// ---------------------------------------------------------------------------
// split-bf16 GEMM, 128x64 tile. C = X*W^T + bias (hi/lo, 3 MFMA products).
// mode 0 (q): epilogue computes q = C @ M_bh via split-MFMA (C->LDS stride-72,
//             MT B-frags direct from global), writes qh/ql bf16 heads layout.
// mode 1 (p1): writes hi/lo bf16 heads layout.
// ---------------------------------------------------------------------------
__global__ __launch_bounds__(256) void gemm_split128(
    const u16* __restrict__ Xh, const u16* __restrict__ Xl,
    const u16* __restrict__ Wh, const u16* __restrict__ Wl,
    const float* __restrict__ bias,
    const u16* __restrict__ MTh, const u16* __restrict__ MTl,
    u16* __restrict__ oh, u16* __restrict__ ol, int mode)
{
    const int K = 1024;
    __shared__ __align__(16) char smem[36864];
    u16* Xs_h = (u16*)smem;              // 128*40
    u16* Xs_l = Xs_h + 128 * 40;
    u16* Ws_h = Xs_l + 128 * 40;         // 64*40
    u16* Ws_l = Ws_h + 64 * 40;          // staging total 30720 B
    u16* Cs_h = (u16*)smem;              // epilogue: 128*72
    u16* Cs_l = Cs_h + 128 * 72;         // total 36864 B

    const int tid = threadIdx.x;
    const int w = tid >> 6, lane = tid & 63;
    const int waveM = w & 1, waveN = w >> 1;
    const int quad = lane >> 4, l16 = lane & 15;
    const int bm = blockIdx.x, bn = blockIdx.y;

    const int xrow = tid >> 1, xko = (tid & 1) * 16;
    const int wrow = tid >> 2, wko = (tid & 3) * 8;

    const u16* xh_g = Xh + (size_t)(bm * 128 + xrow) * K + xko;
    const u16* xl_g = Xl + (size_t)(bm * 128 + xrow) * K + xko;
    const u16* wh_g = Wh + (size_t)(bn * 64 + wrow) * K + wko;
    const u16* wl_g = Wl + (size_t)(bn * 64 + wrow) * K + wko;

    f32x4 acc[4][2] = {};

    for (int k0 = 0; k0 < K; k0 += 32) {
        uint4 xa = *(const uint4*)(xh_g + k0);
        uint4 xb = *(const uint4*)(xh_g + k0 + 8);
        uint4 xc = *(const uint4*)(xl_g + k0);
        uint4 xd = *(const uint4*)(xl_g + k0 + 8);
        uint4 wa = *(const uint4*)(wh_g + k0);
        uint4 wc = *(const uint4*)(wl_g + k0);
        __syncthreads();
        *(uint4*)&Xs_h[xrow * 40 + xko]     = xa;
        *(uint4*)&Xs_h[xrow * 40 + xko + 8] = xb;
        *(uint4*)&Xs_l[xrow * 40 + xko]     = xc;
        *(uint4*)&Xs_l[xrow * 40 + xko + 8] = xd;
        *(uint4*)&Ws_h[wrow * 40 + wko] = wa;
        *(uint4*)&Ws_l[wrow * 40 + wko] = wc;
        __syncthreads();

        short8 ah[4], al[4], bh_[2], bl_[2];
#pragma unroll
        for (int mt = 0; mt < 4; ++mt) {
            int r = (waveM * 64 + mt * 16 + l16) * 40 + quad * 8;
            ah[mt] = *(short8*)&Xs_h[r];
            al[mt] = *(short8*)&Xs_l[r];
        }
#pragma unroll
        for (int nt = 0; nt < 2; ++nt) {
            int r = (waveN * 32 + nt * 16 + l16) * 40 + quad * 8;
            bh_[nt] = *(short8*)&Ws_h[r];
            bl_[nt] = *(short8*)&Ws_l[r];
        }
#pragma unroll
        for (int mt = 0; mt < 4; ++mt)
#pragma unroll
            for (int nt = 0; nt < 2; ++nt) {
                acc[mt][nt] = __builtin_amdgcn_mfma_f32_16x16x32_bf16(ah[mt], bh_[nt], acc[mt][nt], 0, 0, 0);
                acc[mt][nt] = __builtin_amdgcn_mfma_f32_16x16x32_bf16(ah[mt], bl_[nt], acc[mt][nt], 0, 0, 0);
                acc[mt][nt] = __builtin_amdgcn_mfma_f32_16x16x32_bf16(al[mt], bh_[nt], acc[mt][nt], 0, 0, 0);
            }
    }

    const int bh = (bm >> 3) * H_ + bn;   // 8 m-blocks per batch; head = bn

    if (mode == 1) {
#pragma unroll
        for (int mt = 0; mt < 4; ++mt)
#pragma unroll
            for (int nt = 0; nt < 2; ++nt)
#pragma unroll
                for (int r = 0; r < 4; ++r) {
                    int m = bm * 128 + waveM * 64 + mt * 16 + quad * 4 + r;
                    int n = bn * 64 + waveN * 32 + nt * 16 + l16;
                    float val = acc[mt][nt][r] + bias[n];
                    int s = m & 1023, c = n & 63;
                    size_t addr = ((size_t)bh * S_ + s) * 64 + c;
                    u16 hh, ll; splitf(val, hh, ll);
                    oh[addr] = hh; ol[addr] = ll;
                }
        return;
    }

    // mode 0: q = C @ M (split MFMA). C -> LDS stride 72, hi/lo.
    __syncthreads();
#pragma unroll
    for (int mt = 0; mt < 4; ++mt)
#pragma unroll
        for (int nt = 0; nt < 2; ++nt)
#pragma unroll
            for (int r = 0; r < 4; ++r) {
                int i = waveM * 64 + mt * 16 + quad * 4 + r;
                int a = waveN * 32 + nt * 16 + l16;
                float val = acc[mt][nt][r] + bias[bn * 64 + a];
                u16 hh, ll; splitf(val, hh, ll);
                Cs_h[i * 72 + a] = hh;
                Cs_l[i * 72 + a] = ll;
            }
    __syncthreads();

    const u16* MTh_b = MTh + (size_t)bh * 4096;
    const u16* MTl_b = MTl + (size_t)bh * 4096;
    f32x4 qacc[4][2] = {};
#pragma unroll
    for (int ch = 0; ch < 2; ++ch) {
        short8 mh[2], ml[2];
#pragma unroll
        for (int nt = 0; nt < 2; ++nt) {
            int c = waveN * 32 + nt * 16 + l16;
            mh[nt] = *(const short8*)&MTh_b[c * 64 + ch * 32 + quad * 8];
            ml[nt] = *(const short8*)&MTl_b[c * 64 + ch * 32 + quad * 8];
        }
#pragma unroll
        for (int mt = 0; mt < 4; ++mt) {
            int rr = (waveM * 64 + mt * 16 + l16) * 72 + ch * 32 + quad * 8;
            short8 ca = *(short8*)&Cs_h[rr];
            short8 cl = *(short8*)&Cs_l[rr];
#pragma unroll
            for (int nt = 0; nt < 2; ++nt) {
                qacc[mt][nt] = __builtin_amdgcn_mfma_f32_16x16x32_bf16(ca, mh[nt], qacc[mt][nt], 0, 0, 0);
                qacc[mt][nt] = __builtin_amdgcn_mfma_f32_16x16x32_bf16(ca, ml[nt], qacc[mt][nt], 0, 0, 0);
                qacc[mt][nt] = __builtin_amdgcn_mfma_f32_16x16x32_bf16(cl, mh[nt], qacc[mt][nt], 0, 0, 0);
            }
        }
    }
#pragma unroll
    for (int mt = 0; mt < 4; ++mt)
#pragma unroll
        for (int nt = 0; nt < 2; ++nt)
#pragma unroll
            for (int r = 0; r < 4; ++r) {
                int s = (bm & 7) * 128 + waveM * 64 + mt * 16 + quad * 4 + r;
                int c = waveN * 32 + nt * 16 + l16;
                size_t addr = ((size_t)bh * S_ + s) * 64 + c;
                u16 hh, ll; splitf(qacc[mt][nt][r], hh, ll);
                oh[addr] = hh; ol[addr] = ll;
            }
}

// ---------------------------------------------------------------------------
// plain bf16 GEMM 64x64 (round-7 verbatim — PASSING)
// mode 0: out bf16 TRANSPOSED heads layout vT[(bh*64 + d)*S + s]   (v)
// mode 1: out fp32 natural                                          (final)
// ---------------------------------------------------------------------------
__global__ __launch_bounds__(256) void gemm_plain(
    const u16* __restrict__ Xb, const float* __restrict__ Wf,
    const float* __restrict__ bias, u16* __restrict__ outB,
    float* __restrict__ outF, int mode)
{
    const int K = 1024;
    __shared__ __align__(16) u16 Xs[64 * 40];
    __shared__ __align__(16) u16 Ws[64 * 40];

    const int tid = threadIdx.x;
    const int w = tid >> 6, lane = tid & 63;
    const int waveM = w & 1, waveN = w >> 1;
    const int quad = lane >> 4, l16 = lane & 15;
    const int bm = blockIdx.x, bn = blockIdx.y;
    const int lrow = tid >> 2, lkoff = (tid & 3) * 8;

    const u16* xg = Xb + (size_t)(bm * 64 + lrow) * K + lkoff;
    const float* wg = Wf + (size_t)(bn * 64 + lrow) * K + lkoff;

    f32x4 acc[2][2] = {};

    for (int k0 = 0; k0 < K; k0 += 32) {
        uint4 xv = *(const uint4*)(xg + k0);
        float4 w0 = *(const float4*)(wg + k0);
        float4 w1 = *(const float4*)(wg + k0 + 4);
        short8 wp;
        ((u16*)&wp)[0] = f2b(w0.x); ((u16*)&wp)[1] = f2b(w0.y);
        ((u16*)&wp)[2] = f2b(w0.z); ((u16*)&wp)[3] = f2b(w0.w);
        ((u16*)&wp)[4] = f2b(w1.x); ((u16*)&wp)[5] = f2b(w1.y);
        ((u16*)&wp)[6] = f2b(w1.z); ((u16*)&wp)[7] = f2b(w1.w);
        __syncthreads();
        *(uint4*)&Xs[lrow * 40 + lkoff] = xv;
        *(short8*)&Ws[lrow * 40 + lkoff] = wp;
        __syncthreads();

        short8 af[2], bf_[2];
#pragma unroll
        for (int mt = 0; mt < 2; ++mt)
            af[mt] = *(short8*)&Xs[(waveM * 32 + mt * 16 + l16) * 40 + quad * 8];
#pragma unroll
        for (int nt = 0; nt < 2; ++nt)
            bf_[nt] = *(short8*)&Ws[(waveN * 32 + nt * 16 + l16) * 40 + quad * 8];
#pragma unroll
        for (int mt = 0; mt < 2; ++mt)
#pragma unroll
            for (int nt = 0; nt < 2; ++nt)
                acc[mt][nt] = __builtin_amdgcn_mfma_f32_16x16x32_bf16(af[mt], bf_[nt], acc[mt][nt], 0, 0, 0);
    }

#pragma unroll
    for (int mt = 0; mt < 2; ++mt)
#pragma unroll
        for (int nt = 0; nt < 2; ++nt)
#pragma unroll
            for (int r = 0; r < 4; ++r) {
                int m = bm * 64 + waveM * 32 + mt * 16 + quad * 4 + r;
                int n = bn * 64 + waveN * 32 + nt * 16 + l16;
                float val = acc[mt][nt][r] + bias[n];
                if (mode == 0) {
                    int b = m >> 10, s = m & 1023, h = n >> 6, c = n & 63;
                    outB[((size_t)((b * H_ + h) * 64 + c)) * S_ + s] = f2b(val);
                } else {
                    outF[(size_t)m * 1024 + n] = val;
                }
            }
}

// ---------------------------------------------------------------------------
// FUSED logits+softmax+PV (round-10 structure, PASSING) + XCD swizzle:
// grid (64, 32) with x = bh so all 32 i-blocks of one bh share an XCD
// (id = bh + 64*y => id%8 = bh%8) — per-bh p1/vT stays L2-resident.
// ---------------------------------------------------------------------------
__global__ __launch_bounds__(512) void logits_softmax_pv(
    const u16* __restrict__ qh, const u16* __restrict__ ql,
    const u16* __restrict__ p1h, const u16* __restrict__ p1l,
    const u16* __restrict__ vT, float* __restrict__ attn,
    u16* __restrict__ values)
{
    int bh = blockIdx.x, i0 = blockIdx.y * 32;
    int b = bh >> 4, h = bh & 15;
    int tid = threadIdx.x, w = tid >> 6, lane = tid & 63;
    int quad = lane >> 4, l16 = lane & 15;
    int wg = w >> 2, wj = w & 3;

    __shared__ __align__(16) u16 qhs[32 * 72], qls[32 * 72];
    __shared__ __align__(16) u16 p1hs[2][64 * 72], p1ls[2][64 * 72];
    __shared__ __align__(16) u16 Ps[32 * 72];
    __shared__ __align__(16) u16 vs_[64 * 72];
    __shared__ float redm[4][32], reds[4][32];

    {   // stage q (32x64 hi/lo)
        int row = tid >> 4, c0 = (tid & 15) * 4;
        size_t g = ((size_t)bh * S_ + i0 + row) * 64 + c0;
        *(us4*)&qhs[row * 72 + c0] = *(const us4*)&qh[g];
        *(us4*)&qls[row * 72 + c0] = *(const us4*)&ql[g];
    }

    // p1 staging: thread covers (row jl, 8 cols) — tile stride 4096 elems
    const int jl = tid >> 3, c0s = (tid & 7) * 8;
    const size_t gp = ((size_t)bh * S_ + jl) * 64 + c0s;

    uint4 rha = *(const uint4*)&p1h[gp];
    uint4 rla = *(const uint4*)&p1l[gp];
    *(uint4*)&p1hs[0][jl * 72 + c0s] = rha;
    *(uint4*)&p1ls[0][jl * 72 + c0s] = rla;
    uint4 rh1 = *(const uint4*)&p1h[gp + 4096];
    uint4 rl1 = *(const uint4*)&p1l[gp + 4096];
    __syncthreads();    // q + buf0 visible

    short8 ah[2], al[2];
#pragma unroll
    for (int ch = 0; ch < 2; ++ch) {
        ah[ch] = *(short8*)&qhs[(wg * 16 + l16) * 72 + ch * 32 + quad * 8];
        al[ch] = *(short8*)&qls[(wg * 16 + l16) * 72 + ch * 32 + quad * 8];
    }

    f32x4 L[16];
    for (int t = 0; t < 16; ++t) {
        int cur = t & 1;
        uint4 rh2, rl2;
        if (t < 14) {
            size_t gn = gp + (size_t)(t + 2) * 4096;
            rh2 = *(const uint4*)&p1h[gn];
            rl2 = *(const uint4*)&p1l[gn];
        }
        int jr = wj * 16 + l16;
        const u16* Hb = &p1hs[cur][jr * 72];
        const u16* Lb = &p1ls[cur][jr * 72];
        short8 bh0 = *(const short8*)(Hb + quad * 8);
        short8 bh1 = *(const short8*)(Hb + 32 + quad * 8);
        short8 bl0 = *(const short8*)(Lb + quad * 8);
        short8 bl1 = *(const short8*)(Lb + 32 + quad * 8);
        f32x4 a = {};
        a = __builtin_amdgcn_mfma_f32_16x16x32_bf16(ah[0], bh0, a, 0, 0, 0);
        a = __builtin_amdgcn_mfma_f32_16x16x32_bf16(ah[1], bh1, a, 0, 0, 0);
        a = __builtin_amdgcn_mfma_f32_16x16x32_bf16(ah[0], bl0, a, 0, 0, 0);
        a = __builtin_amdgcn_mfma_f32_16x16x32_bf16(ah[1], bl1, a, 0, 0, 0);
        a = __builtin_amdgcn_mfma_f32_16x16x32_bf16(al[0], bh0, a, 0, 0, 0);
        a = __builtin_amdgcn_mfma_f32_16x16x32_bf16(al[1], bh1, a, 0, 0, 0);
        L[t] = a;
        if (t < 15) {
            *(uint4*)&p1hs[1 - cur][jl * 72 + c0s] = rh1;
            *(uint4*)&p1ls[1 - cur][jl * 72 + c0s] = rl1;
            if (t < 14) { rh1 = rh2; rl1 = rl2; }
            __syncthreads();
        }
    }

    // softmax
    float mrow[4], srow[4];
#pragma unroll
    for (int r = 0; r < 4; ++r) {
        float m = L[0][r];
#pragma unroll
        for (int t = 1; t < 16; ++t) m = fmaxf(m, L[t][r]);
#pragma unroll
        for (int off = 1; off < 16; off <<= 1) m = fmaxf(m, __shfl_xor(m, off, 64));
        mrow[r] = m;
    }
    if (l16 == 0)
#pragma unroll
        for (int r = 0; r < 4; ++r) redm[wj][wg * 16 + quad * 4 + r] = mrow[r];
    __syncthreads();
#pragma unroll
    for (int r = 0; r < 4; ++r) {
        int rowg = wg * 16 + quad * 4 + r;
        float m = fmaxf(fmaxf(redm[0][rowg], redm[1][rowg]),
                        fmaxf(redm[2][rowg], redm[3][rowg]));
        float s = 0.f;
#pragma unroll
        for (int t = 0; t < 16; ++t) { L[t][r] = __expf(L[t][r] - m); s += L[t][r]; }
#pragma unroll
        for (int off = 1; off < 16; off <<= 1) s += __shfl_xor(s, off, 64);
        srow[r] = s;
    }
    if (l16 == 0)
#pragma unroll
        for (int r = 0; r < 4; ++r) reds[wj][wg * 16 + quad * 4 + r] = srow[r];
    __syncthreads();
#pragma unroll
    for (int r = 0; r < 4; ++r) {
        int rowg = wg * 16 + quad * 4 + r;
        float inv = 1.0f / (reds[0][rowg] + reds[1][rowg] + reds[2][rowg] + reds[3][rowg]);
        float* arow = attn + ((size_t)bh * S_ + i0 + rowg) * S_;
#pragma unroll
        for (int t = 0; t < 16; ++t) {
            float p = L[t][r] * inv;
            L[t][r] = p;
            __builtin_nontemporal_store(p, &arow[t * 64 + wj * 16 + l16]);
        }
    }

    // ---- PV ----
    const int dv = tid >> 3, jc = (tid & 7) * 8;
    size_t gv = ((size_t)(bh * 64 + dv)) * S_ + jc;
    uint4 rv = *(const uint4*)&vT[gv];

    f32x4 acc_pv = {};
    for (int t = 0; t < 16; ++t) {
        __syncthreads();
#pragma unroll
        for (int r = 0; r < 4; ++r)
            Ps[(wg * 16 + quad * 4 + r) * 72 + wj * 16 + l16] = f2b(L[t][r]);
        *(uint4*)&vs_[dv * 72 + jc] = rv;
        __syncthreads();
        if (t < 15) rv = *(const uint4*)&vT[gv + (size_t)(t + 1) * 64];
        int d = wj * 16 + l16;
#pragma unroll
        for (int cc = 0; cc < 64; cc += 32) {
            short8 af = *(short8*)&Ps[(wg * 16 + l16) * 72 + cc + quad * 8];
            short8 bf = *(short8*)&vs_[d * 72 + cc + quad * 8];
            acc_pv = __builtin_amdgcn_mfma_f32_16x16x32_bf16(af, bf, acc_pv, 0, 0, 0);
        }
    }
#pragma unroll
    for (int r = 0; r < 4; ++r) {
        int i = i0 + wg * 16 + quad * 4 + r;
        int d = wj * 16 + l16;
        values[((size_t)(b * S_ + i)) * E_ + h * 64 + d] = f2b(acc_pv[r]);
    }
}

extern "C" void kernel_launch(void* const* d_in, const int* in_sizes, int n_in,
                              void* d_out, int out_size, void* d_ws, size_t ws_size,
                              hipStream_t stream)
{
    const float* x  = (const float*)d_in[0];
    const float* W0 = (const float*)d_in[1];
    const float* b0 = (const float*)d_in[2];
    const float* W1 = (const float*)d_in[3];
    const float* b1 = (const float*)d_in[4];
    const float* W2 = (const float*)d_in[5];
    const float* b2 = (const float*)d_in[6];
    const float* Wv = (const float*)d_in[7];
    const float* bv = (const float*)d_in[8];
    const float* Wo = (const float*)d_in[9];
    const float* bo = (const float*)d_in[10];
    const float* A  = (const float*)d_in[11];

    float* out  = (float*)d_out;
    float* attn = out + (size_t)B_ * S_ * E_;

    // workspace (~74 MB)
    u16* xh  = (u16*)d_ws;                  // 8 MB
    u16* xl  = xh + 4194304;                // 8 MB
    u16* w0h = xl + 4194304;                // 2 MB
    u16* w0l = w0h + 1048576;
    u16* w1h = w0l + 1048576;
    u16* w1l = w1h + 1048576;
    u16* p1h = w1l + 1048576;               // 8 MB
    u16* p1l = p1h + 4194304;               // 8 MB
    u16* qh  = p1l + 4194304;               // 8 MB
    u16* ql  = qh + 4194304;                // 8 MB
    u16* vT  = ql + 4194304;                // 8 MB (heads-transposed v)
    u16* values = vT + 4194304;             // 8 MB (bf16 natural)
    u16* MTh = values + 4194304;            // 512 KB (transposed M hi)
    u16* MTl = MTh + 262144;                // 512 KB
    float* xsum = (float*)(MTl + 262144);   // 4096
    float* t2n  = xsum + 4096;              // 4096

    split_pair<<<4096, 256, 0, stream>>>(x, xh, xl, 1048576);
    split_pair<<<1024, 256, 0, stream>>>(W0, w0h, w0l, 262144);
    split_pair<<<1024, 256, 0, stream>>>(W1, w1h, w1l, 262144);
    reduce_xsum<<<dim3(4, 4), 256, 0, stream>>>(x, xsum);
    compute_t2k<<<dim3(16, 4), 256, 0, stream>>>(W2, b2, xsum, t2n);
    compute_M<<<BH_, 256, 0, stream>>>(A, t2n, MTh, MTl);

    dim3 gs(32, 16);
    gemm_split128<<<gs, 256, 0, stream>>>(xh, xl, w0h, w0l, b0, MTh, MTl, qh, ql, 0); // q (fused)
    gemm_split128<<<gs, 256, 0, stream>>>(xh, xl, w1h, w1l, b1, nullptr, nullptr, p1h, p1l, 1); // p1

    dim3 gp(64, 16);
    gemm_plain<<<gp, 256, 0, stream>>>(xh, Wv, bv, vT, nullptr, 0);                   // vT

    logits_softmax_pv<<<dim3(64, 32), 512, 0, stream>>>(qh, ql, p1h, p1l, vT, attn, values);

    gemm_plain<<<gp, 256, 0, stream>>>(values, Wo, bo, nullptr, out, 1);
}